// Round 7
// baseline (553.475 us; speedup 1.0000x reference)
//
#include <hip/hip_runtime.h>

// LearnedRouter: logits = x[T,H] @ W[E,H]^T ; softmax ; top-2.
// T=16384, H=4096, E=8. Output flat: scores[T*8] | weights[T*2] | idx[T*2] (fp32).
//
// R7: discriminate "compiler load/compute serialization" vs "pure-read BW
// ceiling". Structure:
//   * W staged to LDS ONCE (full 128 KB) -> exactly ONE __syncthreads in the
//     kernel; the main loop has zero barriers, zero collective drains.
//   * Each wave processes 4 rows as 2 pairs; per pair the 16 float4-positions
//     are split into 4 batches of (2 rows x 4 float4) = 8 loads. Manual
//     ping-pong: batch b+1 is issued into registers xb while batch b (xa) is
//     consumed -> distinct regs force fine-grained vmcnt, keeping 8 KB/wave
//     in flight continuously (16 waves/CU -> 128 KB/CU sustained).
//   * block 1024 (16 waves), grid 256 (1 block/CU, LDS 128 KB).
// VGPR budget: xa 32 + xb 32 + acc 16 + addr ~20 ≈ 105 <= 128 (required for
// a 16-wave block). Spill tripwire: WRITE_SIZE >> 1 MB.

#define ROUTER_H4 1024       // float4 per row (H=4096)
#define ROUTER_E 8

__global__ __launch_bounds__(1024) void learned_router_kernel(
    const float* __restrict__ x, const float* __restrict__ W,
    float* __restrict__ out_scores, float* __restrict__ out_w,
    float* __restrict__ out_idx, int n_rows)
{
    __shared__ float4 wlds[ROUTER_E][ROUTER_H4];   // 128 KB — full W

    const int tid  = (int)threadIdx.x;          // 0..1023
    const int wv   = tid >> 6;                  // wave in block: 0..15
    const int lane = tid & 63;

    const float4* __restrict__ x4 = (const float4*)x;
    const float4* __restrict__ W4 = (const float4*)W;

    // ---- stage ALL of W: 8192 float4 / 1024 threads = 8 each, coalesced ----
#pragma unroll
    for (int k = 0; k < 8; ++k) {
        const int flat = k * 1024 + tid;        // == e*H4 + pos, row-major
        wlds[0][flat] = W4[flat];               // flat covers [E][H4] linearly
    }
    __syncthreads();                            // the ONLY barrier

    // rows: 64 per block; wave wv owns 4 rows, processed as 2 pairs.
    const int rowbase = (int)blockIdx.x * 64 + wv * 4;

    for (int pair = 0; pair < 2; ++pair) {
        const int r0 = rowbase + pair * 2;
        const float4* xr0 = x4 + (size_t)r0 * ROUTER_H4;
        const float4* xr1 = x4 + (size_t)(r0 + 1) * ROUTER_H4;

        float acc[2][ROUTER_E];
#pragma unroll
        for (int e = 0; e < ROUTER_E; ++e) { acc[0][e] = 0.f; acc[1][e] = 0.f; }

        // positions: k*64+lane, k=0..15, in 4 batches of 4.
        float4 xa[2][4], xb[2][4];
#pragma unroll
        for (int j = 0; j < 4; ++j) {           // prologue: batch 0
            xa[0][j] = xr0[j * 64 + lane];
            xa[1][j] = xr1[j * 64 + lane];
        }

#pragma unroll
        for (int b = 0; b < 4; ++b) {
            if (b < 3) {                        // issue batch b+1 while computing b
#pragma unroll
                for (int j = 0; j < 4; ++j) {
                    xb[0][j] = xr0[((b + 1) * 4 + j) * 64 + lane];
                    xb[1][j] = xr1[((b + 1) * 4 + j) * 64 + lane];
                }
            }
#pragma unroll
            for (int j = 0; j < 4; ++j) {
                const int kpos = (b * 4 + j) * 64 + lane;
#pragma unroll
                for (int e = 0; e < ROUTER_E; ++e) {
                    const float4 w4 = wlds[e][kpos];
                    acc[0][e] += xa[0][j].x * w4.x + xa[0][j].y * w4.y
                               + xa[0][j].z * w4.z + xa[0][j].w * w4.w;
                    acc[1][e] += xa[1][j].x * w4.x + xa[1][j].y * w4.y
                               + xa[1][j].z * w4.z + xa[1][j].w * w4.w;
                }
            }
            if (b < 3) {
#pragma unroll
                for (int j = 0; j < 4; ++j) { xa[0][j] = xb[0][j]; xa[1][j] = xb[1][j]; }
            }
        }

        // ---- wave butterfly reduction (64 lanes) ----
#pragma unroll
        for (int off = 32; off > 0; off >>= 1) {
#pragma unroll
            for (int r = 0; r < 2; ++r)
#pragma unroll
                for (int e = 0; e < ROUTER_E; ++e)
                    acc[r][e] += __shfl_xor(acc[r][e], off, 64);
        }

        if (lane == 0) {
#pragma unroll
            for (int r = 0; r < 2; ++r) {
                const int row = r0 + r;
                float m = acc[r][0];
#pragma unroll
                for (int e = 1; e < ROUTER_E; ++e) m = fmaxf(m, acc[r][e]);
                float p[ROUTER_E];
                float s = 0.f;
#pragma unroll
                for (int e = 0; e < ROUTER_E; ++e) { p[e] = __expf(acc[r][e] - m); s += p[e]; }
                const float inv = 1.f / s;
#pragma unroll
                for (int e = 0; e < ROUTER_E; ++e) p[e] *= inv;

                float4* os = (float4*)(out_scores + (size_t)row * ROUTER_E);
                os[0] = make_float4(p[0], p[1], p[2], p[3]);
                os[1] = make_float4(p[4], p[5], p[6], p[7]);

                // top-2, lowest-index tie-break (matches jax.lax.top_k)
                int i0 = 0;
#pragma unroll
                for (int e = 1; e < ROUTER_E; ++e) if (p[e] > p[i0]) i0 = e;
                int i1 = (i0 == 0) ? 1 : 0;
#pragma unroll
                for (int e = 0; e < ROUTER_E; ++e) if (e != i0 && p[e] > p[i1]) i1 = e;

                *(float2*)(out_w + (size_t)row * 2)   = make_float2(p[i0], p[i1]);
                *(float2*)(out_idx + (size_t)row * 2) = make_float2((float)i0, (float)i1);
            }
        }
    }
}

extern "C" void kernel_launch(void* const* d_in, const int* in_sizes, int n_in,
                              void* d_out, int out_size, void* d_ws, size_t ws_size,
                              hipStream_t stream) {
    const float* x = (const float*)d_in[0];
    const float* W = (const float*)d_in[1];
    const int T = in_sizes[0] / (ROUTER_H4 * 4);     // 16384
    (void)n_in; (void)d_ws; (void)ws_size; (void)out_size;

    float* out = (float*)d_out;
    float* out_scores = out;
    float* out_w   = out + (size_t)T * ROUTER_E;
    float* out_idx = out_w + (size_t)T * 2;

    const int rows_per_block = 64;                   // 16 waves x 4 rows
    const int grid = (T + rows_per_block - 1) / rows_per_block;  // 256 = #CUs
    learned_router_kernel<<<grid, 1024, 0, stream>>>(x, W, out_scores, out_w, out_idx, T);
}